// Round 6
// baseline (170.614 us; speedup 1.0000x reference)
//
#include <hip/hip_runtime.h>
#include <math.h>

// Problem constants
#define B 512
#define E 256
#define L 1024  // 32*32

typedef float f32x4 __attribute__((ext_vector_type(4)));
typedef unsigned long long u64;

// Workspace layout (floats)
#define O_Q    0u            // B*L   raw_q
#define O_SOMN 524288u       // L*E
#define O_IRS  786432u       // B     (1/rowsum)
#define O_PART 786944u       // 16*L  colsum partials
#define O_BMU  803328u       // B u64 (even float offset -> 8B aligned)

// ---------------------------------------------------------------------------
// K1: dist^2(Z, SOM) fused with packed argmin -> bmu[b] = (bits(d2)<<32)|j.
// 64x64 tiles, K-chunks of 64 over E=256, 256 threads, 4x4 micro-tile.
// atomicMin on u64 is order-independent => deterministic, first-index ties.
// ---------------------------------------------------------------------------
__global__ __launch_bounds__(256) void dist_bmu_kernel(const float* __restrict__ Zg,
                                                       const float* __restrict__ Wg,
                                                       u64* __restrict__ bmu) {
    __shared__ float Zs[64][67];
    __shared__ float Ws[64][67];
    __shared__ u64 red[64][16];
    const int tid = threadIdx.x;
    const int tb = blockIdx.x >> 4;   // 0..7
    const int tn = blockIdx.x & 15;   // 0..15
    const int b0 = tb * 64, n0 = tn * 64;
    const int ty = tid >> 4, tx = tid & 15;

    float acc[4][4];
#pragma unroll
    for (int i = 0; i < 4; ++i)
#pragma unroll
        for (int j = 0; j < 4; ++j) acc[i][j] = 0.f;

    for (int kc = 0; kc < E; kc += 64) {
        const int c4 = tx * 4;
#pragma unroll
        for (int s = 0; s < 4; ++s) {
            const int r = ty + 16 * s;
            float4 zv = *(const float4*)(Zg + (size_t)(b0 + r) * E + kc + c4);
            Zs[r][c4 + 0] = zv.x; Zs[r][c4 + 1] = zv.y;
            Zs[r][c4 + 2] = zv.z; Zs[r][c4 + 3] = zv.w;
            float4 wv = *(const float4*)(Wg + (size_t)(n0 + r) * E + kc + c4);
            Ws[r][c4 + 0] = wv.x; Ws[r][c4 + 1] = wv.y;
            Ws[r][c4 + 2] = wv.z; Ws[r][c4 + 3] = wv.w;
        }
        __syncthreads();
#pragma unroll 4
        for (int k = 0; k < 64; ++k) {
            float zr[4], wr[4];
#pragma unroll
            for (int i = 0; i < 4; ++i) zr[i] = Zs[ty * 4 + i][k];
#pragma unroll
            for (int j = 0; j < 4; ++j) wr[j] = Ws[tx * 4 + j][k];
#pragma unroll
            for (int i = 0; i < 4; ++i)
#pragma unroll
                for (int j = 0; j < 4; ++j) {
                    float d = zr[i] - wr[j];
                    acc[i][j] = fmaf(d, d, acc[i][j]);
                }
        }
        __syncthreads();
    }
    // per-thread packed min over its 4 j (ascending j, strict < => first index)
#pragma unroll
    for (int i = 0; i < 4; ++i) {
        float best = acc[i][0];
        int bj = 0;
#pragma unroll
        for (int j = 1; j < 4; ++j)
            if (acc[i][j] < best) { best = acc[i][j]; bj = j; }
        red[ty * 4 + i][tx] = ((u64)__float_as_uint(best) << 32) |
                              (unsigned)(n0 + tx * 4 + bj);
    }
    __syncthreads();
    if (tid < 64) {
        u64 m = red[tid][0];
#pragma unroll
        for (int t = 1; t < 16; ++t) {
            const u64 v = red[tid][t];
            if (v < m) m = v;
        }
        atomicMin(&bmu[b0 + tid], m);
    }
}

// ---------------------------------------------------------------------------
// K2: delta[b, hw, e] = eta*h(bmu[b],hw) * (Z[b,e] - SOM[hw,e]) — 537 MB writer.
// R2-proven burst pattern (one 16B NT store per thread, block exits), glued
// into 1024-thread blocks: 32768 dispatches instead of 131072.
// ---------------------------------------------------------------------------
__global__ __launch_bounds__(1024) void delta_kernel(const float* __restrict__ Zg,
                                                     const float* __restrict__ Wg,
                                                     const u64* __restrict__ bmu,
                                                     const int* __restrict__ step,
                                                     float* __restrict__ delta) {
    const int b = blockIdx.x >> 6;
    const int hw = ((blockIdx.x & 63) << 4) + (threadIdx.x >> 6);
    const int lane = threadIdx.x & 63;

    const int u = (int)(bmu[b] & 0xffffffffULL);
    const int ur = u >> 5, uc = u & 31;
    const float n = (float)step[0];
    const float decay = expf(-n * 0.01f);
    const float eta = 0.3f * decay;
    const float sigma = 16.0f * decay;
    const float inv2s2 = 1.0f / (2.0f * sigma * sigma);
    const int i = hw >> 5, j = hw & 31;
    const float dr = (float)(ur - i), dc = (float)(uc - j);
    const float hs = eta * expf(-(dr * dr + dc * dc) * inv2s2);

    const float4 z = *(const float4*)(Zg + (size_t)b * E + lane * 4);
    const float4 w = *(const float4*)(Wg + (size_t)hw * E + lane * 4);
    f32x4 o;
    o.x = hs * (z.x - w.x);
    o.y = hs * (z.y - w.y);
    o.z = hs * (z.z - w.z);
    o.w = hs * (z.w - w.w);
    f32x4* dst = (f32x4*)(delta + ((size_t)b * L + hw) * E + lane * 4);
    __builtin_nontemporal_store(o, dst);
}

// ---------------------------------------------------------------------------
// K3: SOM_new[hw,e] = SOM + (1/B)*(sum_b hv*Z - (sum_b hv)*SOM)
// hv[512] built cooperatively in LDS (2 exp/thread), then broadcast-read.
// ---------------------------------------------------------------------------
__global__ __launch_bounds__(256) void update_kernel(const float* __restrict__ Zg,
                                                     const float* __restrict__ Wg,
                                                     const u64* __restrict__ bmu,
                                                     const int* __restrict__ step,
                                                     float* __restrict__ somn) {
    __shared__ float hv[B];
    const int hw = blockIdx.x;
    const int e = threadIdx.x;
    const int i = hw >> 5, j = hw & 31;
    const float n = (float)step[0];
    const float decay = expf(-n * 0.01f);
    const float eta = 0.3f * decay;
    const float sigma = 16.0f * decay;
    const float inv2s2 = 1.0f / (2.0f * sigma * sigma);
#pragma unroll
    for (int s = 0; s < 2; ++s) {
        const int b = e + s * 256;
        const int u = (int)(bmu[b] & 0xffffffffULL);
        const int ur = u >> 5, uc = u & 31;
        const float dr = (float)(ur - i), dc = (float)(uc - j);
        hv[b] = eta * expf(-(dr * dr + dc * dc) * inv2s2);
    }
    __syncthreads();

    float acc = 0.f, hsum = 0.f;
#pragma unroll 8
    for (int b = 0; b < B; ++b) {
        const float h = hv[b];                 // LDS broadcast
        acc = fmaf(h, Zg[(size_t)b * E + e], acc);
        hsum += h;
    }
    const float w = Wg[(size_t)hw * E + e];
    somn[(size_t)hw * E + e] = w + (1.0f / (float)B) * (acc - hsum * w);
}

// ---------------------------------------------------------------------------
// K4: raw_q[b,j] = 1/(1+dist(Z, SOM_new)) — same tiling as K1.
// ---------------------------------------------------------------------------
__global__ __launch_bounds__(256) void distq_kernel(const float* __restrict__ Zg,
                                                    const float* __restrict__ Wg,
                                                    float* __restrict__ out) {
    __shared__ float Zs[64][67];
    __shared__ float Ws[64][67];
    const int tid = threadIdx.x;
    const int tb = blockIdx.x >> 4;
    const int tn = blockIdx.x & 15;
    const int b0 = tb * 64, n0 = tn * 64;
    const int ty = tid >> 4, tx = tid & 15;

    float acc[4][4];
#pragma unroll
    for (int i = 0; i < 4; ++i)
#pragma unroll
        for (int j = 0; j < 4; ++j) acc[i][j] = 0.f;

    for (int kc = 0; kc < E; kc += 64) {
        const int c4 = tx * 4;
#pragma unroll
        for (int s = 0; s < 4; ++s) {
            const int r = ty + 16 * s;
            float4 zv = *(const float4*)(Zg + (size_t)(b0 + r) * E + kc + c4);
            Zs[r][c4 + 0] = zv.x; Zs[r][c4 + 1] = zv.y;
            Zs[r][c4 + 2] = zv.z; Zs[r][c4 + 3] = zv.w;
            float4 wv = *(const float4*)(Wg + (size_t)(n0 + r) * E + kc + c4);
            Ws[r][c4 + 0] = wv.x; Ws[r][c4 + 1] = wv.y;
            Ws[r][c4 + 2] = wv.z; Ws[r][c4 + 3] = wv.w;
        }
        __syncthreads();
#pragma unroll 4
        for (int k = 0; k < 64; ++k) {
            float zr[4], wr[4];
#pragma unroll
            for (int i = 0; i < 4; ++i) zr[i] = Zs[ty * 4 + i][k];
#pragma unroll
            for (int j = 0; j < 4; ++j) wr[j] = Ws[tx * 4 + j][k];
#pragma unroll
            for (int i = 0; i < 4; ++i)
#pragma unroll
                for (int j = 0; j < 4; ++j) {
                    float d = zr[i] - wr[j];
                    acc[i][j] = fmaf(d, d, acc[i][j]);
                }
        }
        __syncthreads();
    }
#pragma unroll
    for (int i = 0; i < 4; ++i) {
        const int b = b0 + ty * 4 + i;
        float4 v;
        v.x = 1.f / (1.f + sqrtf(acc[i][0]));
        v.y = 1.f / (1.f + sqrtf(acc[i][1]));
        v.z = 1.f / (1.f + sqrtf(acc[i][2]));
        v.w = 1.f / (1.f + sqrtf(acc[i][3]));
        *(float4*)(out + (size_t)b * L + n0 + tx * 4) = v;
    }
}

// K5: irs[b] = 1 / sum_j raw_q[b, j]
__global__ __launch_bounds__(256) void rowsum_kernel(const float* __restrict__ q,
                                                     float* __restrict__ irs) {
    const int b = blockIdx.x;
    const int tid = threadIdx.x;
    float acc = 0.f;
#pragma unroll
    for (int s = 0; s < 4; ++s) acc += q[(size_t)b * L + tid + s * 256];
    __shared__ float sm[256];
    sm[tid] = acc;
    __syncthreads();
    for (int st = 128; st > 0; st >>= 1) {
        if (tid < st) sm[tid] += sm[tid + st];
        __syncthreads();
    }
    if (tid == 0) irs[b] = 1.0f / sm[0];
}

// K6: colsum partials: part[c][j] = sum_{b in chunk c} q[b][j]*irs[b]
__global__ __launch_bounds__(256) void colsum_part_kernel(const float* __restrict__ q,
                                                          const float* __restrict__ irs,
                                                          float* __restrict__ part) {
    const int j = (blockIdx.x & 3) * 256 + threadIdx.x;
    const int c = blockIdx.x >> 2;   // 0..15
    const int b0 = c * 32;
    float acc = 0.f;
#pragma unroll 8
    for (int bo = 0; bo < 32; ++bo)
        acc = fmaf(q[(size_t)(b0 + bo) * L + j], irs[b0 + bo], acc);
    part[(size_t)c * L + j] = acc;
}

// K7: kl[b] = T/S - log(S); cs[j] reduced from 16 partials in-kernel (fixed order).
__global__ __launch_bounds__(256) void kl_kernel(const float* __restrict__ q,
                                                 const float* __restrict__ irs,
                                                 const float* __restrict__ part,
                                                 float* __restrict__ kl) {
    const int b = blockIdx.x;
    const int tid = threadIdx.x;
    const float irsb = irs[b];
    float S = 0.f, T = 0.f;
#pragma unroll
    for (int s = 0; s < 4; ++s) {
        const int j = tid + s * 256;
        float csj = 0.f;
#pragma unroll
        for (int c = 0; c < 16; ++c) csj += part[(size_t)c * L + j];
        const float qq = q[(size_t)b * L + j] * irsb;
        const float ic = 1.0f / csj;
        const float rp = qq * qq * ic;
        S += rp;
        T = fmaf(rp, logf(qq * ic), T);
    }
    __shared__ float sS[256], sT[256];
    sS[tid] = S; sT[tid] = T;
    __syncthreads();
    for (int st = 128; st > 0; st >>= 1) {
        if (tid < st) { sS[tid] += sS[tid + st]; sT[tid] += sT[tid + st]; }
        __syncthreads();
    }
    if (tid == 0) kl[b] = sT[0] / sS[0] - logf(sS[0]);
}

extern "C" void kernel_launch(void* const* d_in, const int* in_sizes, int n_in,
                              void* d_out, int out_size, void* d_ws, size_t ws_size,
                              hipStream_t stream) {
    const float* Zg = (const float*)d_in[0];
    const float* Wg = (const float*)d_in[1];
    const int* step = (const int*)d_in[2];
    float* out = (float*)d_out;          // [0,512): kl_loss, [512,...): delta
    float* ws = (float*)d_ws;

    float* q    = ws + O_Q;
    float* somn = ws + O_SOMN;
    float* irs  = ws + O_IRS;
    float* part = ws + O_PART;
    u64*   bmu  = (u64*)(ws + O_BMU);

    float* kl    = out;
    float* delta = out + B;

    hipMemsetAsync(bmu, 0xFF, B * sizeof(u64), stream);
    hipLaunchKernelGGL(dist_bmu_kernel, dim3(128), dim3(256), 0, stream, Zg, Wg, bmu);
    hipLaunchKernelGGL(delta_kernel, dim3(32768), dim3(1024), 0, stream, Zg, Wg, bmu, step, delta);
    hipLaunchKernelGGL(update_kernel, dim3(L), dim3(256), 0, stream, Zg, Wg, bmu, step, somn);
    hipLaunchKernelGGL(distq_kernel, dim3(128), dim3(256), 0, stream, Zg, somn, q);
    hipLaunchKernelGGL(rowsum_kernel, dim3(B), dim3(256), 0, stream, q, irs);
    hipLaunchKernelGGL(colsum_part_kernel, dim3(64), dim3(256), 0, stream, q, irs, part);
    hipLaunchKernelGGL(kl_kernel, dim3(B), dim3(256), 0, stream, q, irs, part, kl);
}

// Round 7
// 163.273 us; speedup vs baseline: 1.0450x; 1.0450x over previous
//
#include <hip/hip_runtime.h>
#include <math.h>

// Problem constants
#define B 512
#define E 256
#define L 1024  // 32*32

typedef float f32x4 __attribute__((ext_vector_type(4)));
typedef unsigned long long u64;

// Workspace layout (floats)
#define O_Q    0u            // B*L   raw_q
#define O_SOMN 524288u       // L*E
#define O_IRS  786432u       // B     (1/rowsum)
#define O_PART 786944u       // 16*L  colsum partials
#define O_PRS  803328u       // 16*B  rowsum partials (from distq)
#define O_H    811520u       // B*L   eta-scaled h
#define O_BMU  1335808u      // B u64 (even float offset -> 8B aligned)

// ---------------------------------------------------------------------------
// K1: dist^2(Z, SOM) fused with packed argmin -> bmu[b] = (bits(d2)<<32)|j.
// atomicMin(u64) is order-independent => deterministic, first-index ties.
// ---------------------------------------------------------------------------
__global__ __launch_bounds__(256) void dist_bmu_kernel(const float* __restrict__ Zg,
                                                       const float* __restrict__ Wg,
                                                       u64* __restrict__ bmu) {
    __shared__ float Zs[64][67];
    __shared__ float Ws[64][67];
    __shared__ u64 red[64][16];
    const int tid = threadIdx.x;
    const int tb = blockIdx.x >> 4;   // 0..7
    const int tn = blockIdx.x & 15;   // 0..15
    const int b0 = tb * 64, n0 = tn * 64;
    const int ty = tid >> 4, tx = tid & 15;

    float acc[4][4];
#pragma unroll
    for (int i = 0; i < 4; ++i)
#pragma unroll
        for (int j = 0; j < 4; ++j) acc[i][j] = 0.f;

    for (int kc = 0; kc < E; kc += 64) {
        const int c4 = tx * 4;
#pragma unroll
        for (int s = 0; s < 4; ++s) {
            const int r = ty + 16 * s;
            float4 zv = *(const float4*)(Zg + (size_t)(b0 + r) * E + kc + c4);
            Zs[r][c4 + 0] = zv.x; Zs[r][c4 + 1] = zv.y;
            Zs[r][c4 + 2] = zv.z; Zs[r][c4 + 3] = zv.w;
            float4 wv = *(const float4*)(Wg + (size_t)(n0 + r) * E + kc + c4);
            Ws[r][c4 + 0] = wv.x; Ws[r][c4 + 1] = wv.y;
            Ws[r][c4 + 2] = wv.z; Ws[r][c4 + 3] = wv.w;
        }
        __syncthreads();
#pragma unroll 4
        for (int k = 0; k < 64; ++k) {
            float zr[4], wr[4];
#pragma unroll
            for (int i = 0; i < 4; ++i) zr[i] = Zs[ty * 4 + i][k];
#pragma unroll
            for (int j = 0; j < 4; ++j) wr[j] = Ws[tx * 4 + j][k];
#pragma unroll
            for (int i = 0; i < 4; ++i)
#pragma unroll
                for (int j = 0; j < 4; ++j) {
                    float d = zr[i] - wr[j];
                    acc[i][j] = fmaf(d, d, acc[i][j]);
                }
        }
        __syncthreads();
    }
#pragma unroll
    for (int i = 0; i < 4; ++i) {
        float best = acc[i][0];
        int bj = 0;
#pragma unroll
        for (int j = 1; j < 4; ++j)
            if (acc[i][j] < best) { best = acc[i][j]; bj = j; }
        red[ty * 4 + i][tx] = ((u64)__float_as_uint(best) << 32) |
                              (unsigned)(n0 + tx * 4 + bj);
    }
    __syncthreads();
    if (tid < 64) {
        u64 m = red[tid][0];
#pragma unroll
        for (int t = 1; t < 16; ++t) {
            const u64 v = red[tid][t];
            if (v < m) m = v;
        }
        atomicMin(&bmu[b0 + tid], m);
    }
}

// K2: h[b, hw] = eta * exp(-lattice_d2(bmu[b], hw) / (2 sigma^2))
__global__ __launch_bounds__(256) void h_kernel(const u64* __restrict__ bmu,
                                                const int* __restrict__ step,
                                                float* __restrict__ h) {
    const int b = blockIdx.x;
    const int u = (int)(bmu[b] & 0xffffffffULL);
    const int ur = u >> 5, uc = u & 31;
    const float n = (float)step[0];
    const float decay = expf(-n * 0.01f);
    const float eta = 0.3f * decay;
    const float sigma = 16.0f * decay;
    const float inv2s2 = 1.0f / (2.0f * sigma * sigma);
#pragma unroll
    for (int s = 0; s < 4; ++s) {
        const int t = threadIdx.x + s * 256;
        const int i = t >> 5, j = t & 31;
        const float dr = (float)(ur - i), dc = (float)(uc - j);
        h[(size_t)b * L + t] = eta * expf(-(dr * dr + dc * dc) * inv2s2);
    }
}

// K3: delta[b, hw, e] = h_s[b,hw] * (Z[b,e] - SOM[hw,e]) — the 537 MB writer.
// EXACT R5-proven form: 131072 blocks x 256 thr, one 16B NT store per thread.
__global__ __launch_bounds__(256) void delta_kernel(const float* __restrict__ Zg,
                                                    const float* __restrict__ Wg,
                                                    const float* __restrict__ h,
                                                    float* __restrict__ delta) {
    const int bid = blockIdx.x;              // 512 * 256 blocks
    const int b = bid >> 8;
    const int hw = ((bid & 255) << 2) + (threadIdx.x >> 6);
    const int lane = threadIdx.x & 63;
    const float hs = h[(size_t)b * L + hw];
    const float4 z = *(const float4*)(Zg + (size_t)b * E + lane * 4);
    const float4 w = *(const float4*)(Wg + (size_t)hw * E + lane * 4);
    f32x4 o;
    o.x = hs * (z.x - w.x);
    o.y = hs * (z.y - w.y);
    o.z = hs * (z.z - w.z);
    o.w = hs * (z.w - w.w);
    f32x4* dst = (f32x4*)(delta + ((size_t)b * L + hw) * E + lane * 4);
    __builtin_nontemporal_store(o, dst);
}

// K4: SOM_new[hw,e] = SOM + (1/B)*(sum_b h*Z - (sum_b h)*SOM)  (R5-proven form)
__global__ __launch_bounds__(256) void update_kernel(const float* __restrict__ Zg,
                                                     const float* __restrict__ Wg,
                                                     const float* __restrict__ h,
                                                     float* __restrict__ somn) {
    const int hw = blockIdx.x;
    const int e = threadIdx.x;
    float acc = 0.f, hsum = 0.f;
#pragma unroll 8
    for (int b = 0; b < B; ++b) {
        const float hv = h[(size_t)b * L + hw];
        acc = fmaf(hv, Zg[(size_t)b * E + e], acc);
        hsum += hv;
    }
    const float w = Wg[(size_t)hw * E + e];
    somn[(size_t)hw * E + e] = w + (1.0f / (float)B) * (acc - hsum * w);
}

// ---------------------------------------------------------------------------
// K5: raw_q = 1/(1+dist(Z, SOM_new)) + fixed-order per-block row partial sums
// part_rs[tn][b] = sum over this block's 64 j of q[b][j].
// ---------------------------------------------------------------------------
__global__ __launch_bounds__(256) void distq_kernel(const float* __restrict__ Zg,
                                                    const float* __restrict__ Wg,
                                                    float* __restrict__ out,
                                                    float* __restrict__ part_rs) {
    __shared__ float Zs[64][67];
    __shared__ float Ws[64][67];
    __shared__ float red[64][16];
    const int tid = threadIdx.x;
    const int tb = blockIdx.x >> 4;
    const int tn = blockIdx.x & 15;
    const int b0 = tb * 64, n0 = tn * 64;
    const int ty = tid >> 4, tx = tid & 15;

    float acc[4][4];
#pragma unroll
    for (int i = 0; i < 4; ++i)
#pragma unroll
        for (int j = 0; j < 4; ++j) acc[i][j] = 0.f;

    for (int kc = 0; kc < E; kc += 64) {
        const int c4 = tx * 4;
#pragma unroll
        for (int s = 0; s < 4; ++s) {
            const int r = ty + 16 * s;
            float4 zv = *(const float4*)(Zg + (size_t)(b0 + r) * E + kc + c4);
            Zs[r][c4 + 0] = zv.x; Zs[r][c4 + 1] = zv.y;
            Zs[r][c4 + 2] = zv.z; Zs[r][c4 + 3] = zv.w;
            float4 wv = *(const float4*)(Wg + (size_t)(n0 + r) * E + kc + c4);
            Ws[r][c4 + 0] = wv.x; Ws[r][c4 + 1] = wv.y;
            Ws[r][c4 + 2] = wv.z; Ws[r][c4 + 3] = wv.w;
        }
        __syncthreads();
#pragma unroll 4
        for (int k = 0; k < 64; ++k) {
            float zr[4], wr[4];
#pragma unroll
            for (int i = 0; i < 4; ++i) zr[i] = Zs[ty * 4 + i][k];
#pragma unroll
            for (int j = 0; j < 4; ++j) wr[j] = Ws[tx * 4 + j][k];
#pragma unroll
            for (int i = 0; i < 4; ++i)
#pragma unroll
                for (int j = 0; j < 4; ++j) {
                    float d = zr[i] - wr[j];
                    acc[i][j] = fmaf(d, d, acc[i][j]);
                }
        }
        __syncthreads();
    }
#pragma unroll
    for (int i = 0; i < 4; ++i) {
        const int b = b0 + ty * 4 + i;
        float4 v;
        v.x = 1.f / (1.f + sqrtf(acc[i][0]));
        v.y = 1.f / (1.f + sqrtf(acc[i][1]));
        v.z = 1.f / (1.f + sqrtf(acc[i][2]));
        v.w = 1.f / (1.f + sqrtf(acc[i][3]));
        *(float4*)(out + (size_t)b * L + n0 + tx * 4) = v;
        red[ty * 4 + i][tx] = v.x + v.y + v.z + v.w;   // fixed order within thread
    }
    __syncthreads();
    if (tid < 64) {
        float s = red[tid][0];
#pragma unroll
        for (int t = 1; t < 16; ++t) s += red[tid][t];  // ascending tx = ascending j
        part_rs[(size_t)tn * B + b0 + tid] = s;
    }
}

// K6: irs[b] = 1 / sum_{tn} part_rs[tn][b]   (2 blocks x 256)
__global__ __launch_bounds__(256) void rowsum_reduce_kernel(const float* __restrict__ part_rs,
                                                            float* __restrict__ irs) {
    const int b = blockIdx.x * 256 + threadIdx.x;
    float s = 0.f;
#pragma unroll
    for (int tn = 0; tn < 16; ++tn) s += part_rs[(size_t)tn * B + b];
    irs[b] = 1.0f / s;
}

// K7: colsum partials: part[c][j] = sum_{b in chunk c} q[b][j]*irs[b]
__global__ __launch_bounds__(256) void colsum_part_kernel(const float* __restrict__ q,
                                                          const float* __restrict__ irs,
                                                          float* __restrict__ part) {
    const int j = (blockIdx.x & 3) * 256 + threadIdx.x;
    const int c = blockIdx.x >> 2;   // 0..15
    const int b0 = c * 32;
    float acc = 0.f;
#pragma unroll 8
    for (int bo = 0; bo < 32; ++bo)
        acc = fmaf(q[(size_t)(b0 + bo) * L + j], irs[b0 + bo], acc);
    part[(size_t)c * L + j] = acc;
}

// K8: kl[b] = T/S - log(S); cs[j] reduced from 16 partials in-kernel (fixed order).
__global__ __launch_bounds__(256) void kl_kernel(const float* __restrict__ q,
                                                 const float* __restrict__ irs,
                                                 const float* __restrict__ part,
                                                 float* __restrict__ kl) {
    const int b = blockIdx.x;
    const int tid = threadIdx.x;
    const float irsb = irs[b];
    float S = 0.f, T = 0.f;
#pragma unroll
    for (int s = 0; s < 4; ++s) {
        const int j = tid + s * 256;
        float csj = 0.f;
#pragma unroll
        for (int c = 0; c < 16; ++c) csj += part[(size_t)c * L + j];
        const float qq = q[(size_t)b * L + j] * irsb;
        const float ic = 1.0f / csj;
        const float rp = qq * qq * ic;
        S += rp;
        T = fmaf(rp, logf(qq * ic), T);
    }
    __shared__ float sS[256], sT[256];
    sS[tid] = S; sT[tid] = T;
    __syncthreads();
    for (int st = 128; st > 0; st >>= 1) {
        if (tid < st) { sS[tid] += sS[tid + st]; sT[tid] += sT[tid + st]; }
        __syncthreads();
    }
    if (tid == 0) kl[b] = sT[0] / sS[0] - logf(sS[0]);
}

extern "C" void kernel_launch(void* const* d_in, const int* in_sizes, int n_in,
                              void* d_out, int out_size, void* d_ws, size_t ws_size,
                              hipStream_t stream) {
    const float* Zg = (const float*)d_in[0];
    const float* Wg = (const float*)d_in[1];
    const int* step = (const int*)d_in[2];
    float* out = (float*)d_out;          // [0,512): kl_loss, [512,...): delta
    float* ws = (float*)d_ws;

    float* q    = ws + O_Q;
    float* somn = ws + O_SOMN;
    float* irs  = ws + O_IRS;
    float* part = ws + O_PART;
    float* prs  = ws + O_PRS;
    float* h    = ws + O_H;
    u64*   bmu  = (u64*)(ws + O_BMU);

    float* kl    = out;
    float* delta = out + B;

    hipMemsetAsync(bmu, 0xFF, B * sizeof(u64), stream);
    hipLaunchKernelGGL(dist_bmu_kernel, dim3(128), dim3(256), 0, stream, Zg, Wg, bmu);
    hipLaunchKernelGGL(h_kernel, dim3(B), dim3(256), 0, stream, bmu, step, h);
    hipLaunchKernelGGL(delta_kernel, dim3(B * 256), dim3(256), 0, stream, Zg, Wg, h, delta);
    hipLaunchKernelGGL(update_kernel, dim3(L), dim3(256), 0, stream, Zg, Wg, h, somn);
    hipLaunchKernelGGL(distq_kernel, dim3(128), dim3(256), 0, stream, Zg, somn, q, prs);
    hipLaunchKernelGGL(rowsum_reduce_kernel, dim3(2), dim3(256), 0, stream, prs, irs);
    hipLaunchKernelGGL(colsum_part_kernel, dim3(64), dim3(256), 0, stream, q, irs, part);
    hipLaunchKernelGGL(kl_kernel, dim3(B), dim3(256), 0, stream, q, irs, part, kl);
}

// Round 8
// 145.551 us; speedup vs baseline: 1.1722x; 1.1218x over previous
//
#include <hip/hip_runtime.h>
#include <math.h>

// Problem constants
#define B 512
#define E 256
#define L 1024  // 32*32

typedef float f32x4 __attribute__((ext_vector_type(4)));
typedef unsigned long long u64;

// Workspace layout (floats)
#define O_Q     0u           // B*L   raw_q
#define O_SOMN  524288u      // L*E
#define O_PART  786432u      // 16*L  colsum partials
#define O_PRS   802816u      // 16*B  rowsum partials (from distq)
#define O_H     811008u      // B*L   eta-scaled h
#define O_BMUP  1335296u     // 16*B u64 packed per-tile argmin candidates

// ---------------------------------------------------------------------------
// K1: dist^2(Z, SOM) fused argmin -> bmupart[tn][b] = (bits(d2)<<32)|j (packed).
// No atomics: per-j-tile candidates, reduced later (u64 min, order-indep).
// ---------------------------------------------------------------------------
__global__ __launch_bounds__(256) void dist_bmu_kernel(const float* __restrict__ Zg,
                                                       const float* __restrict__ Wg,
                                                       u64* __restrict__ bmupart) {
    __shared__ float Zs[64][67];
    __shared__ float Ws[64][67];
    __shared__ u64 red[64][16];
    const int tid = threadIdx.x;
    const int tb = blockIdx.x >> 4;   // 0..7
    const int tn = blockIdx.x & 15;   // 0..15
    const int b0 = tb * 64, n0 = tn * 64;
    const int ty = tid >> 4, tx = tid & 15;

    float acc[4][4];
#pragma unroll
    for (int i = 0; i < 4; ++i)
#pragma unroll
        for (int j = 0; j < 4; ++j) acc[i][j] = 0.f;

    for (int kc = 0; kc < E; kc += 64) {
        const int c4 = tx * 4;
#pragma unroll
        for (int s = 0; s < 4; ++s) {
            const int r = ty + 16 * s;
            float4 zv = *(const float4*)(Zg + (size_t)(b0 + r) * E + kc + c4);
            Zs[r][c4 + 0] = zv.x; Zs[r][c4 + 1] = zv.y;
            Zs[r][c4 + 2] = zv.z; Zs[r][c4 + 3] = zv.w;
            float4 wv = *(const float4*)(Wg + (size_t)(n0 + r) * E + kc + c4);
            Ws[r][c4 + 0] = wv.x; Ws[r][c4 + 1] = wv.y;
            Ws[r][c4 + 2] = wv.z; Ws[r][c4 + 3] = wv.w;
        }
        __syncthreads();
#pragma unroll 4
        for (int k = 0; k < 64; ++k) {
            float zr[4], wr[4];
#pragma unroll
            for (int i = 0; i < 4; ++i) zr[i] = Zs[ty * 4 + i][k];
#pragma unroll
            for (int j = 0; j < 4; ++j) wr[j] = Ws[tx * 4 + j][k];
#pragma unroll
            for (int i = 0; i < 4; ++i)
#pragma unroll
                for (int j = 0; j < 4; ++j) {
                    float d = zr[i] - wr[j];
                    acc[i][j] = fmaf(d, d, acc[i][j]);
                }
        }
        __syncthreads();
    }
#pragma unroll
    for (int i = 0; i < 4; ++i) {
        float best = acc[i][0];
        int bj = 0;
#pragma unroll
        for (int j = 1; j < 4; ++j)
            if (acc[i][j] < best) { best = acc[i][j]; bj = j; }
        red[ty * 4 + i][tx] = ((u64)__float_as_uint(best) << 32) |
                              (unsigned)(n0 + tx * 4 + bj);
    }
    __syncthreads();
    if (tid < 64) {
        u64 m = red[tid][0];
#pragma unroll
        for (int t = 1; t < 16; ++t) {
            const u64 v = red[tid][t];
            if (v < m) m = v;
        }
        bmupart[(size_t)tn * B + b0 + tid] = m;
    }
}

// K2: reduce bmu candidates + h[b, hw] = eta * exp(-lattice_d2 / (2 sigma^2))
__global__ __launch_bounds__(256) void h_kernel(const u64* __restrict__ bmupart,
                                                const int* __restrict__ step,
                                                float* __restrict__ h) {
    const int b = blockIdx.x;
    u64 m = bmupart[b];
#pragma unroll
    for (int tn = 1; tn < 16; ++tn) {
        const u64 v = bmupart[(size_t)tn * B + b];
        if (v < m) m = v;
    }
    const int u = (int)(m & 0xffffffffULL);
    const int ur = u >> 5, uc = u & 31;
    const float n = (float)step[0];
    const float decay = expf(-n * 0.01f);
    const float eta = 0.3f * decay;
    const float sigma = 16.0f * decay;
    const float inv2s2 = 1.0f / (2.0f * sigma * sigma);
#pragma unroll
    for (int s = 0; s < 4; ++s) {
        const int t = threadIdx.x + s * 256;
        const int i = t >> 5, j = t & 31;
        const float dr = (float)(ur - i), dc = (float)(uc - j);
        h[(size_t)b * L + t] = eta * expf(-(dr * dr + dc * dc) * inv2s2);
    }
}

// ---------------------------------------------------------------------------
// K3 mega: blocks 0..1023 -> SOM update; blocks 1024.. -> delta writer.
// Update's compute hides under delta's NT-write stream (same dispatch).
// Delta per-thread code is EXACTLY the R5-proven form.
// ---------------------------------------------------------------------------
__global__ __launch_bounds__(256) void delta_update_kernel(const float* __restrict__ Zg,
                                                           const float* __restrict__ Wg,
                                                           const float* __restrict__ h,
                                                           float* __restrict__ somn,
                                                           float* __restrict__ delta) {
    if (blockIdx.x < 1024) {
        // --- update path: SOM_new[hw,e] = SOM + (1/B)*(sum_b h*Z - (sum_b h)*SOM)
        const int hw = blockIdx.x;
        const int e = threadIdx.x;
        float acc = 0.f, hsum = 0.f;
#pragma unroll 8
        for (int b = 0; b < B; ++b) {
            const float hv = h[(size_t)b * L + hw];
            acc = fmaf(hv, Zg[(size_t)b * E + e], acc);
            hsum += hv;
        }
        const float w = Wg[(size_t)hw * E + e];
        somn[(size_t)hw * E + e] = w + (1.0f / (float)B) * (acc - hsum * w);
        return;
    }
    // --- delta path (R5-proven): one 16B NT store per thread
    const int bid = blockIdx.x - 1024;       // 512 * 256 blocks
    const int b = bid >> 8;
    const int hw = ((bid & 255) << 2) + (threadIdx.x >> 6);
    const int lane = threadIdx.x & 63;
    const float hs = h[(size_t)b * L + hw];
    const float4 z = *(const float4*)(Zg + (size_t)b * E + lane * 4);
    const float4 w = *(const float4*)(Wg + (size_t)hw * E + lane * 4);
    f32x4 o;
    o.x = hs * (z.x - w.x);
    o.y = hs * (z.y - w.y);
    o.z = hs * (z.z - w.z);
    o.w = hs * (z.w - w.w);
    f32x4* dst = (f32x4*)(delta + ((size_t)b * L + hw) * E + lane * 4);
    __builtin_nontemporal_store(o, dst);
}

// ---------------------------------------------------------------------------
// K4: raw_q = 1/(1+dist(Z, SOM_new)) + fixed-order per-block row partials
// part_rs[tn][b] = sum over this block's 64 j of q[b][j].
// ---------------------------------------------------------------------------
__global__ __launch_bounds__(256) void distq_kernel(const float* __restrict__ Zg,
                                                    const float* __restrict__ Wg,
                                                    float* __restrict__ out,
                                                    float* __restrict__ part_rs) {
    __shared__ float Zs[64][67];
    __shared__ float Ws[64][67];
    __shared__ float red[64][16];
    const int tid = threadIdx.x;
    const int tb = blockIdx.x >> 4;
    const int tn = blockIdx.x & 15;
    const int b0 = tb * 64, n0 = tn * 64;
    const int ty = tid >> 4, tx = tid & 15;

    float acc[4][4];
#pragma unroll
    for (int i = 0; i < 4; ++i)
#pragma unroll
        for (int j = 0; j < 4; ++j) acc[i][j] = 0.f;

    for (int kc = 0; kc < E; kc += 64) {
        const int c4 = tx * 4;
#pragma unroll
        for (int s = 0; s < 4; ++s) {
            const int r = ty + 16 * s;
            float4 zv = *(const float4*)(Zg + (size_t)(b0 + r) * E + kc + c4);
            Zs[r][c4 + 0] = zv.x; Zs[r][c4 + 1] = zv.y;
            Zs[r][c4 + 2] = zv.z; Zs[r][c4 + 3] = zv.w;
            float4 wv = *(const float4*)(Wg + (size_t)(n0 + r) * E + kc + c4);
            Ws[r][c4 + 0] = wv.x; Ws[r][c4 + 1] = wv.y;
            Ws[r][c4 + 2] = wv.z; Ws[r][c4 + 3] = wv.w;
        }
        __syncthreads();
#pragma unroll 4
        for (int k = 0; k < 64; ++k) {
            float zr[4], wr[4];
#pragma unroll
            for (int i = 0; i < 4; ++i) zr[i] = Zs[ty * 4 + i][k];
#pragma unroll
            for (int j = 0; j < 4; ++j) wr[j] = Ws[tx * 4 + j][k];
#pragma unroll
            for (int i = 0; i < 4; ++i)
#pragma unroll
                for (int j = 0; j < 4; ++j) {
                    float d = zr[i] - wr[j];
                    acc[i][j] = fmaf(d, d, acc[i][j]);
                }
        }
        __syncthreads();
    }
#pragma unroll
    for (int i = 0; i < 4; ++i) {
        const int b = b0 + ty * 4 + i;
        float4 v;
        v.x = 1.f / (1.f + sqrtf(acc[i][0]));
        v.y = 1.f / (1.f + sqrtf(acc[i][1]));
        v.z = 1.f / (1.f + sqrtf(acc[i][2]));
        v.w = 1.f / (1.f + sqrtf(acc[i][3]));
        *(float4*)(out + (size_t)b * L + n0 + tx * 4) = v;
        red[ty * 4 + i][tx] = v.x + v.y + v.z + v.w;   // fixed order within thread
    }
    __syncthreads();
    if (tid < 64) {
        float s = red[tid][0];
#pragma unroll
        for (int t = 1; t < 16; ++t) s += red[tid][t];  // ascending tx = ascending j
        part_rs[(size_t)tn * B + b0 + tid] = s;
    }
}

// K5: colsum partials with inline irs: part[c][j] = sum_{b in chunk} q[b][j]*irs[b]
__global__ __launch_bounds__(256) void colsum_part_kernel(const float* __restrict__ q,
                                                          const float* __restrict__ prs,
                                                          float* __restrict__ part) {
    __shared__ float sirs[32];
    const int j = (blockIdx.x & 3) * 256 + threadIdx.x;
    const int c = blockIdx.x >> 2;   // 0..15
    const int b0 = c * 32;
    if (threadIdx.x < 32) {
        float s = 0.f;
#pragma unroll
        for (int tn = 0; tn < 16; ++tn) s += prs[(size_t)tn * B + b0 + threadIdx.x];
        sirs[threadIdx.x] = 1.0f / s;
    }
    __syncthreads();
    float acc = 0.f;
#pragma unroll 8
    for (int bo = 0; bo < 32; ++bo)
        acc = fmaf(q[(size_t)(b0 + bo) * L + j], sirs[bo], acc);
    part[(size_t)c * L + j] = acc;
}

// K6: kl[b] = T/S - log(S); irs[b] and cs[j] computed inline (fixed order).
__global__ __launch_bounds__(256) void kl_kernel(const float* __restrict__ q,
                                                 const float* __restrict__ prs,
                                                 const float* __restrict__ part,
                                                 float* __restrict__ kl) {
    const int b = blockIdx.x;
    const int tid = threadIdx.x;
    float rs = 0.f;
#pragma unroll
    for (int tn = 0; tn < 16; ++tn) rs += prs[(size_t)tn * B + b];  // uniform -> broadcast
    const float irsb = 1.0f / rs;
    float S = 0.f, T = 0.f;
#pragma unroll
    for (int s = 0; s < 4; ++s) {
        const int j = tid + s * 256;
        float csj = 0.f;
#pragma unroll
        for (int c = 0; c < 16; ++c) csj += part[(size_t)c * L + j];
        const float qq = q[(size_t)b * L + j] * irsb;
        const float ic = 1.0f / csj;
        const float rp = qq * qq * ic;
        S += rp;
        T = fmaf(rp, logf(qq * ic), T);
    }
    __shared__ float sS[256], sT[256];
    sS[tid] = S; sT[tid] = T;
    __syncthreads();
    for (int st = 128; st > 0; st >>= 1) {
        if (tid < st) { sS[tid] += sS[tid + st]; sT[tid] += sT[tid + st]; }
        __syncthreads();
    }
    if (tid == 0) kl[b] = sT[0] / sS[0] - logf(sS[0]);
}

extern "C" void kernel_launch(void* const* d_in, const int* in_sizes, int n_in,
                              void* d_out, int out_size, void* d_ws, size_t ws_size,
                              hipStream_t stream) {
    const float* Zg = (const float*)d_in[0];
    const float* Wg = (const float*)d_in[1];
    const int* step = (const int*)d_in[2];
    float* out = (float*)d_out;          // [0,512): kl_loss, [512,...): delta
    float* ws = (float*)d_ws;

    float* q    = ws + O_Q;
    float* somn = ws + O_SOMN;
    float* part = ws + O_PART;
    float* prs  = ws + O_PRS;
    float* h    = ws + O_H;
    u64*   bmup = (u64*)(ws + O_BMUP);

    float* kl    = out;
    float* delta = out + B;

    hipLaunchKernelGGL(dist_bmu_kernel, dim3(128), dim3(256), 0, stream, Zg, Wg, bmup);
    hipLaunchKernelGGL(h_kernel, dim3(B), dim3(256), 0, stream, bmup, step, h);
    hipLaunchKernelGGL(delta_update_kernel, dim3(1024 + B * 256), dim3(256), 0, stream,
                       Zg, Wg, h, somn, delta);
    hipLaunchKernelGGL(distq_kernel, dim3(128), dim3(256), 0, stream, Zg, somn, q, prs);
    hipLaunchKernelGGL(colsum_part_kernel, dim3(64), dim3(256), 0, stream, q, prs, part);
    hipLaunchKernelGGL(kl_kernel, dim3(B), dim3(256), 0, stream, q, prs, part, kl);
}